// Round 1
// baseline (309.259 us; speedup 1.0000x reference)
//
#include <hip/hip_runtime.h>

// OFT block-diagonal rotation (Cayley-Neumann, 5 terms).
// x: [8192, 4096] fp32, weight: [64, 2016] fp32 -> out: [8192, 4096] fp32.
// BLOCK = 64, R = 64.

#define NELEM 2016

__device__ __forceinline__ int triu_off(int i) {
    // offset of row i in triu_indices(64, k=1) row-major packing
    return i * 63 - (i * (i - 1)) / 2;
}

// Kernel 1: build rot[r][k][c] = (I + 2Q + 2Q^2 + 2Q^3 + 2Q^4)[k][c], fp32.
// One workgroup per r-block; 1024 threads; thread owns a 1x4 row segment.
__global__ __launch_bounds__(1024) void oft_rot_kernel(const float* __restrict__ w,
                                                       float* __restrict__ rot) {
    __shared__ float Q[64][64];      // 16 KB
    __shared__ float P[2][64][64];   // 32 KB

    const int r   = blockIdx.x;
    const float* __restrict__ wr = w + r * NELEM;
    const int tid = threadIdx.x;          // 0..1023
    const int i   = tid >> 4;             // row 0..63
    const int j0  = (tid & 15) << 2;      // col 0,4,...,60

    float racc[4];
#pragma unroll
    for (int t = 0; t < 4; ++t) {
        const int j = j0 + t;
        float v;
        if (i < j)      v =  wr[triu_off(i) + (j - i - 1)];
        else if (i > j) v = -wr[triu_off(j) + (i - j - 1)];
        else            v = 0.f;
        Q[i][j]    = v;
        P[0][i][j] = v;
        racc[t] = (i == j ? 1.f : 0.f) + 2.f * v;
    }
    __syncthreads();

    int cur = 0;
#pragma unroll
    for (int p = 2; p < 5; ++p) {
        float a0 = 0.f, a1 = 0.f, a2 = 0.f, a3 = 0.f;
#pragma unroll
        for (int k = 0; k < 64; ++k) {
            const float  pv = P[cur][i][k];
            const float4 qv = *(const float4*)&Q[k][j0];
            a0 = fmaf(pv, qv.x, a0);
            a1 = fmaf(pv, qv.y, a1);
            a2 = fmaf(pv, qv.z, a2);
            a3 = fmaf(pv, qv.w, a3);
        }
        // writes go to the other buffer; no reader of it this iteration
        P[cur ^ 1][i][j0 + 0] = a0;
        P[cur ^ 1][i][j0 + 1] = a1;
        P[cur ^ 1][i][j0 + 2] = a2;
        P[cur ^ 1][i][j0 + 3] = a3;
        racc[0] += 2.f * a0;
        racc[1] += 2.f * a1;
        racc[2] += 2.f * a2;
        racc[3] += 2.f * a3;
        __syncthreads();
        cur ^= 1;
    }

    float4 o = make_float4(racc[0], racc[1], racc[2], racc[3]);
    *(float4*)&rot[(size_t)r * 4096 + i * 64 + j0] = o;
}

// Kernel 2: out[n, r*64+c] = sum_k x[n, r*64+k] * rot[r][k][c].
// lane = token; x row slice lives in 64 VGPRs; rot addresses are wave-uniform
// (blockIdx + loop counters only) -> scalar loads; inner loop is v_fmac(s, v).
__global__ __launch_bounds__(256, 3) void oft_apply_kernel(const float* __restrict__ x,
                                                           const float* __restrict__ rot,
                                                           float* __restrict__ out) {
    const int lane = threadIdx.x & 63;
    const int wv   = threadIdx.x >> 6;
    const int r    = blockIdx.x;                       // 0..63
    const int n    = blockIdx.y * 256 + wv * 64 + lane; // token

    const float* __restrict__ xp = x + (size_t)n * 4096 + r * 64;
    const float* __restrict__ rt = rot + (size_t)r * 4096;  // rot[r][k][c]

    float xr[64];
#pragma unroll
    for (int q = 0; q < 16; ++q) {
        const float4 v = *(const float4*)(xp + q * 4);
        xr[q * 4 + 0] = v.x;
        xr[q * 4 + 1] = v.y;
        xr[q * 4 + 2] = v.z;
        xr[q * 4 + 3] = v.w;
    }

    float* __restrict__ op = out + (size_t)n * 4096 + r * 64;

    for (int cc = 0; cc < 64; cc += 8) {
        float acc[8] = {0.f, 0.f, 0.f, 0.f, 0.f, 0.f, 0.f, 0.f};
#pragma unroll
        for (int k = 0; k < 64; ++k) {
            const float xv = xr[k];
#pragma unroll
            for (int j = 0; j < 8; ++j)
                acc[j] = fmaf(rt[k * 64 + cc + j], xv, acc[j]);
        }
        float4 o0 = make_float4(acc[0], acc[1], acc[2], acc[3]);
        float4 o1 = make_float4(acc[4], acc[5], acc[6], acc[7]);
        *(float4*)(op + cc)     = o0;
        *(float4*)(op + cc + 4) = o1;
    }
}

extern "C" void kernel_launch(void* const* d_in, const int* in_sizes, int n_in,
                              void* d_out, int out_size, void* d_ws, size_t ws_size,
                              hipStream_t stream) {
    const float* x = (const float*)d_in[0];   // [8192, 4096]
    const float* w = (const float*)d_in[1];   // [64, 2016]
    float* out = (float*)d_out;               // [8192, 4096]
    float* rot = (float*)d_ws;                // [64, 64, 64] = 1 MB scratch

    oft_rot_kernel<<<64, 1024, 0, stream>>>(w, rot);
    oft_apply_kernel<<<dim3(64, 32), 256, 0, stream>>>(x, rot, out);
}

// Round 2
// 250.028 us; speedup vs baseline: 1.2369x; 1.2369x over previous
//
#include <hip/hip_runtime.h>

// OFT block-diagonal rotation (Cayley-Neumann, 5 terms).
// x: [8192, 4096] fp32, weight: [64, 2016] fp32 -> out: [8192, 4096] fp32.
// BLOCK = 64, R = 64.

#define NELEM 2016

__device__ __forceinline__ int triu_off(int i) {
    // offset of row i in triu_indices(64, k=1) row-major packing
    return i * 63 - (i * (i - 1)) / 2;
}

__device__ __forceinline__ float skew_val(const float* __restrict__ wr, int i, int j) {
    if (i < j) return  wr[triu_off(i) + (j - i - 1)];
    if (i > j) return -wr[triu_off(j) + (i - j - 1)];
    return 0.f;
}

// Kernel 1: rot[r][k][c] = (I + 2Q + 2Q^2 + 2Q^3 + 2Q^4)[k][c].
// Grid: (r=64, row-tile=4). Each WG owns 16 rows of the chain; only those rows
// of P^(p-1) are needed to form rows of P^p (right-multiply by Q).
__global__ __launch_bounds__(256) void oft_rot_kernel(const float* __restrict__ w,
                                                      float* __restrict__ rot) {
    __shared__ float Q[64][64];        // 16 KB, full Q for this r
    __shared__ float Pl[2][16][65];    // 8.3 KB, padded: kills same-bank reads

    const int r    = blockIdx.x;
    const int tile = blockIdx.y;                 // 0..3
    const float* __restrict__ wr = w + r * NELEM;
    const int tid = threadIdx.x;
    const int il  = tid >> 4;                    // 0..15 local row
    const int j0  = (tid & 15) << 2;             // col 0,4,...,60
    const int gi  = tile * 16 + il;              // global row 0..63

#pragma unroll
    for (int m = 0; m < 4; ++m) {
        const int i = il + 16 * m;
#pragma unroll
        for (int t = 0; t < 4; ++t)
            Q[i][j0 + t] = skew_val(wr, i, j0 + t);
    }
    __syncthreads();

    float racc[4];
#pragma unroll
    for (int t = 0; t < 4; ++t) {
        const float qv = Q[gi][j0 + t];
        Pl[0][il][j0 + t] = qv;
        racc[t] = (gi == j0 + t ? 1.f : 0.f) + 2.f * qv;
    }
    __syncthreads();

    int cur = 0;
#pragma unroll
    for (int p = 2; p < 5; ++p) {
        float a0 = 0.f, a1 = 0.f, a2 = 0.f, a3 = 0.f;
#pragma unroll 8
        for (int k = 0; k < 64; ++k) {
            const float  pv = Pl[cur][il][k];
            const float4 qv = *(const float4*)&Q[k][j0];
            a0 = fmaf(pv, qv.x, a0);
            a1 = fmaf(pv, qv.y, a1);
            a2 = fmaf(pv, qv.z, a2);
            a3 = fmaf(pv, qv.w, a3);
        }
        Pl[cur ^ 1][il][j0 + 0] = a0;
        Pl[cur ^ 1][il][j0 + 1] = a1;
        Pl[cur ^ 1][il][j0 + 2] = a2;
        Pl[cur ^ 1][il][j0 + 3] = a3;
        racc[0] += 2.f * a0;
        racc[1] += 2.f * a1;
        racc[2] += 2.f * a2;
        racc[3] += 2.f * a3;
        __syncthreads();
        cur ^= 1;
    }

    *(float4*)&rot[(size_t)r * 4096 + gi * 64 + j0] =
        make_float4(racc[0], racc[1], racc[2], racc[3]);
}

// Kernel 2: out[n, r*64+c] = sum_k x[n, r*64+k] * rot[r][k][c].
// Grid (r=64, token-tile=64). WG = 128 tokens x 64 cols, 256 threads.
// lane -> contiguous columns (coalesced full-line loads & stores);
// rot + x tile staged in LDS; thread computes 8 tokens x 4 cols.
__global__ __launch_bounds__(256, 3) void oft_apply_kernel(const float* __restrict__ x,
                                                           const float* __restrict__ rot,
                                                           float* __restrict__ out) {
    __shared__ float rotS[64][64];     // 16 KB
    __shared__ float xs[128][65];      // 33.3 KB, +1 pad for conflict-free reads

    const int r   = blockIdx.x;
    const int tok0 = blockIdx.y * 128;
    const int tid = threadIdx.x;

    // stage rot[r]: 4096 floats = 1024 float4, linear, coalesced
    {
        const float4* __restrict__ src = (const float4*)(rot + (size_t)r * 4096);
        float4* dst = (float4*)&rotS[0][0];
#pragma unroll
        for (int p = 0; p < 4; ++p)
            dst[p * 256 + tid] = src[p * 256 + tid];
    }
    // stage x tile: 128 rows x 64 floats; 16 float4 per row, full-line coalesced
#pragma unroll
    for (int p = 0; p < 8; ++p) {
        const int f   = p * 256 + tid;     // float4 index 0..2047
        const int row = f >> 4;
        const int c   = (f & 15) << 2;
        const float4 v = *(const float4*)(x + (size_t)(tok0 + row) * 4096 + r * 64 + c);
        xs[row][c + 0] = v.x;
        xs[row][c + 1] = v.y;
        xs[row][c + 2] = v.z;
        xs[row][c + 3] = v.w;
    }
    __syncthreads();

    const int cq = tid & 15;           // 16 col groups x 4 cols
    const int tq = tid >> 4;           // 16 token groups x 8 tokens
    const int c0 = cq << 2;
    const float* __restrict__ xbase = &xs[tq * 8][0];

    float acc[8][4];
#pragma unroll
    for (int m = 0; m < 8; ++m)
#pragma unroll
        for (int t = 0; t < 4; ++t) acc[m][t] = 0.f;

#pragma unroll 8
    for (int k = 0; k < 64; ++k) {
        const float4 rv = *(const float4*)&rotS[k][c0];
#pragma unroll
        for (int m = 0; m < 8; ++m) {
            const float xv = xbase[m * 65 + k];
            acc[m][0] = fmaf(xv, rv.x, acc[m][0]);
            acc[m][1] = fmaf(xv, rv.y, acc[m][1]);
            acc[m][2] = fmaf(xv, rv.z, acc[m][2]);
            acc[m][3] = fmaf(xv, rv.w, acc[m][3]);
        }
    }

#pragma unroll
    for (int m = 0; m < 8; ++m) {
        const int n = tok0 + tq * 8 + m;
        *(float4*)(out + (size_t)n * 4096 + r * 64 + c0) =
            make_float4(acc[m][0], acc[m][1], acc[m][2], acc[m][3]);
    }
}

extern "C" void kernel_launch(void* const* d_in, const int* in_sizes, int n_in,
                              void* d_out, int out_size, void* d_ws, size_t ws_size,
                              hipStream_t stream) {
    const float* x = (const float*)d_in[0];   // [8192, 4096]
    const float* w = (const float*)d_in[1];   // [64, 2016]
    float* out = (float*)d_out;               // [8192, 4096]
    float* rot = (float*)d_ws;                // [64, 64, 64] = 1 MB scratch

    oft_rot_kernel<<<dim3(64, 4), 256, 0, stream>>>(w, rot);
    oft_apply_kernel<<<dim3(64, 64), 256, 0, stream>>>(x, rot, out);
}